// Round 1
// 303.821 us; speedup vs baseline: 1.0396x; 1.0396x over previous
//
#include <hip/hip_runtime.h>

#define NROWS 8192   // N == M == 8192
#define DDIM  512
#define OUTN  8192

typedef int   i32x4  __attribute__((ext_vector_type(4)));
typedef int   i32x8  __attribute__((ext_vector_type(8)));
typedef float f32x16 __attribute__((ext_vector_type(16)));

// ---------------------------------------------------------------------------
// Fragment layout for mfma_scale_f32_32x32x64_f8f6f4 (A and B identical):
// lane l holds row (l&31), k-bytes (l>>5)*32 .. +31 of a 64-k window.
// Storage: off(row,k) = (row>>5)*16384        // 32-row group
//                     + (k>>6)*2048           // 64-k window h = 0..7
//                     + ((k>>5)&1)*1024       // k-half  (lane>>5)
//                     + (row&31)*32 + (k&31)  // = lane*32 + b
// A wave's 64 lanes read 2 KB contiguous per (group,h): 2x dwordx4/lane.
//
// Prep: one block (4 waves) per 32-row group. Wave w handles rows w*8..w*8+7,
// one row per iteration: 2 KB contiguous row read, sq-norm shfl-reduce,
// fp8 cvt, stage int2 into the 16 KB LDS group image at the swizzled offset
// (bank conflicts here are irrelevant: 16 KB total), then one barrier and a
// fully-coalesced 16 KB linear LDS->global flush (dwordx4, block-contiguous).
// ---------------------------------------------------------------------------
__global__ void __launch_bounds__(256)
rbf_prep(const float* __restrict__ x, const float* __restrict__ y,
         unsigned char* __restrict__ xs, unsigned char* __restrict__ ys,
         float* __restrict__ x2, float* __restrict__ y2) {
    __shared__ unsigned char lbuf[16384];
    const int tid  = threadIdx.x;
    const int lane = tid & 63;
    const int w    = tid >> 6;

    int grp = blockIdx.x;                       // 0..511
    const float* src; unsigned char* dst; float* nrm;
    if (grp < 256) { src = x; dst = xs; nrm = x2; }
    else           { grp -= 256; src = y; dst = ys; nrm = y2; }

    // lane covers k = lane*8 .. +7:  h = lane>>3, khalf = (lane>>2)&1, b = (lane&3)*8
    const int loff_base = (lane >> 3) * 2048 + ((lane >> 2) & 1) * 1024 + (lane & 3) * 8;

#pragma unroll
    for (int j = 0; j < 8; ++j) {
        const int r   = w * 8 + j;              // row within group (0..31)
        const int row = grp * 32 + r;
        const float* p = src + (size_t)row * DDIM + lane * 8;
        float4 v0 = *(const float4*)(p);
        float4 v1 = *(const float4*)(p + 4);

        float s = v0.x * v0.x + v0.y * v0.y + v0.z * v0.z + v0.w * v0.w
                + v1.x * v1.x + v1.y * v1.y + v1.z * v1.z + v1.w * v1.w;

        int lo = __builtin_amdgcn_cvt_pk_fp8_f32(v0.x, v0.y, 0, false);
        lo     = __builtin_amdgcn_cvt_pk_fp8_f32(v0.z, v0.w, lo, true);
        int hi = __builtin_amdgcn_cvt_pk_fp8_f32(v1.x, v1.y, 0, false);
        hi     = __builtin_amdgcn_cvt_pk_fp8_f32(v1.z, v1.w, hi, true);

        *(int2*)(lbuf + loff_base + r * 32) = make_int2(lo, hi);

#pragma unroll
        for (int o = 32; o > 0; o >>= 1) s += __shfl_down(s, o, 64);
        if (lane == 0) nrm[row] = s;
    }

    __syncthreads();
    unsigned char* gdst = dst + (size_t)grp * 16384;
#pragma unroll
    for (int it = 0; it < 4; ++it)
        *(i32x4*)(gdst + it * 4096 + tid * 16) =
            *(const i32x4*)(lbuf + it * 4096 + tid * 16);
}

// ---------------------------------------------------------------------------
// Fused GEMM + RBF epilogue, MX-fp8 (scale = 1.0), BARRIER-FREE, 32x32x64.
// 128x128 block tile, 4 waves (2x2), wave = 2x2 of 32x32x64 MFMAs over
// 8 k-windows. vs the 16x16x128 version: fragment regs halve (32 vs 64),
// launch_bounds(256,3) lifts occupancy to 12 waves/CU, and the 32x32 C/D
// layout makes every store instruction cover two FULL 128 B lines
// (lanes 0-31 = 32 consecutive floats of one row). Nontemporal stores keep
// the 256 MiB output stream from thrashing the 8 MB fp8 working set in L2/L3.
// ---------------------------------------------------------------------------
__global__ void __launch_bounds__(256, 3)
rbf_gemm(const unsigned char* __restrict__ xs,
         const unsigned char* __restrict__ ys,
         const float* __restrict__ x2, const float* __restrict__ y2,
         const float* __restrict__ gamma, float* __restrict__ out) {
    const int tid  = threadIdx.x;
    const int lane = tid & 63;
    const int w    = tid >> 6;        // wave 0..3
    const int wm   = w & 1;           // wave row (0..1)
    const int wn   = w >> 1;          // wave col (0..1)

    const int bm = blockIdx.x & 63;   // fast-varying -> consecutive blocks
    const int bn = blockIdx.x >> 6;   //   share the B tile (L2 locality)
    const int row0 = bm * 128;
    const int col0 = bn * 128;

    f32x16 acc[2][2] = {};

    // fragment base: 32-row group (bm*4 + wm*2 + mi), window h, lane*32
    const unsigned char* abase = xs + (size_t)(bm * 4 + wm * 2) * 16384 + lane * 32;
    const unsigned char* bbase = ys + (size_t)(bn * 4 + wn * 2) * 16384 + lane * 32;

#pragma unroll 2
    for (int h = 0; h < 8; ++h) {
        i32x8 af[2], bf[2];
#pragma unroll
        for (int mi = 0; mi < 2; ++mi) {
            const unsigned char* p = abase + mi * 16384 + h * 2048;
            i32x4 lo = *(const i32x4*)(p);
            i32x4 hi = *(const i32x4*)(p + 16);
            af[mi] = __builtin_shufflevector(lo, hi, 0, 1, 2, 3, 4, 5, 6, 7);
        }
#pragma unroll
        for (int ni = 0; ni < 2; ++ni) {
            const unsigned char* p = bbase + ni * 16384 + h * 2048;
            i32x4 lo = *(const i32x4*)(p);
            i32x4 hi = *(const i32x4*)(p + 16);
            bf[ni] = __builtin_shufflevector(lo, hi, 0, 1, 2, 3, 4, 5, 6, 7);
        }
#pragma unroll
        for (int mi = 0; mi < 2; ++mi)
#pragma unroll
            for (int ni = 0; ni < 2; ++ni)
                acc[mi][ni] = __builtin_amdgcn_mfma_scale_f32_32x32x64_f8f6f4(
                    af[mi], bf[ni], acc[mi][ni],
                    0, 0,          // cbsz/blgp = fp8 e4m3
                    0, 0x7F,       // A scale = 1.0 (E8M0 127)
                    0, 0x7F);      // B scale = 1.0
    }

    // Epilogue: out[r][c] = exp(-g*(x2[r]+y2[c]-2*xy))
    // C/D layout (32x32): col = lane&31, row = (r&3) + 8*(r>>2) + 4*(lane>>5).
    const float g  = gamma[0];
    const int   rq = (lane >> 5) * 4;   // 0 or 4
    const int   cl = lane & 31;
#pragma unroll
    for (int mi = 0; mi < 2; ++mi) {
        const int rbase = row0 + wm * 64 + mi * 32;
        float xn[16];
#pragma unroll
        for (int r = 0; r < 16; ++r)
            xn[r] = x2[rbase + (r & 3) + 8 * (r >> 2) + rq];
#pragma unroll
        for (int ni = 0; ni < 2; ++ni) {
            const int col = col0 + wn * 64 + ni * 32 + cl;
            const float yn = y2[col];
#pragma unroll
            for (int r = 0; r < 16; ++r) {
                const int row = rbase + (r & 3) + 8 * (r >> 2) + rq;
                const float s = xn[r] + yn - 2.0f * acc[mi][ni][r];
                __builtin_nontemporal_store(__expf(-g * s),
                                            out + (size_t)row * OUTN + col);
            }
        }
    }
}

extern "C" void kernel_launch(void* const* d_in, const int* in_sizes, int n_in,
                              void* d_out, int out_size, void* d_ws, size_t ws_size,
                              hipStream_t stream) {
    const float* x     = (const float*)d_in[0];
    const float* y     = (const float*)d_in[1];
    const float* gamma = (const float*)d_in[2];
    float* out = (float*)d_out;

    // workspace: xs (4 MB, swizzled fp8) | ys (4 MB) | x2 (32 KB) | y2 (32 KB)
    char* ws = (char*)d_ws;
    unsigned char* xs = (unsigned char*)ws;
    unsigned char* ys = (unsigned char*)(ws + (size_t)NROWS * DDIM);
    float* x2 = (float*)(ws + (size_t)NROWS * DDIM * 2);
    float* y2 = (float*)(ws + (size_t)NROWS * DDIM * 2 + NROWS * 4);

    rbf_prep<<<512, 256, 0, stream>>>(x, y, xs, ys, x2, y2);
    rbf_gemm<<<4096, 256, 0, stream>>>(xs, ys, x2, y2, gamma, out);
}